// Round 1
// baseline (524.796 us; speedup 1.0000x reference)
//
#include <hip/hip_runtime.h>
#include <math.h>

#define C_ 128
#define MID 8
#define CS 262144            // channel stride = 64*64*64
static __device__ __forceinline__ float sigmoidf_(float z) {
    return 1.0f / (1.0f + __expf(-z));
}
#define SQRT8 2.8284271247461903f   // 2*sqrt(2)

// ---------------------------------------------------------------------------
// Kernel 1: gap[b*128+c] = 2*sqrt(2) * mean over 32^3 of corner samples
// one block per (b,c); 256 threads; fully coalesced float2 row loads (evens kept)
// ---------------------------------------------------------------------------
__global__ __launch_bounds__(256) void gap_kernel(const float* __restrict__ x,
                                                  float* __restrict__ gap) {
    const int bc = blockIdx.x;                 // 0..255  (b*128 + c)
    const float* xb = x + (size_t)bc * CS;
    float s = 0.0f;
    // 1024 even-(d,h) rows, 32 float2 each = 32768 float2 loads, keep .x
    for (int j = threadIdx.x; j < 32768; j += 256) {
        int d  = j >> 10;
        int h  = (j >> 5) & 31;
        int f2 = j & 31;
        const float2* row = (const float2*)(xb + (size_t)(((2 * d) * 64 + 2 * h) * 64));
        s += row[f2].x;
    }
    __shared__ float red[256];
    red[threadIdx.x] = s;
    __syncthreads();
    for (int off = 128; off > 0; off >>= 1) {
        if (threadIdx.x < off) red[threadIdx.x] += red[threadIdx.x + off];
        __syncthreads();
    }
    if (threadIdx.x == 0) gap[bc] = red[0] * (SQRT8 / 32768.0f);
}

// ---------------------------------------------------------------------------
// Kernel 2: gout[b*128+c] = MLP_g(gap)[b,c]   (tiny; single block)
// ---------------------------------------------------------------------------
__global__ __launch_bounds__(256) void gmlp_kernel(const float* __restrict__ gap,
                                                   const float* __restrict__ gw1,
                                                   const float* __restrict__ gb1,
                                                   const float* __restrict__ gw2,
                                                   const float* __restrict__ gb2,
                                                   float* __restrict__ gout) {
    __shared__ float hid[2][MID];
    const int t = threadIdx.x;
    if (t < 2 * MID) {
        int b = t >> 3, m = t & 7;
        float a = gb1[m];
        for (int c = 0; c < C_; ++c) a += gw1[m * C_ + c] * gap[b * C_ + c];
        hid[b][m] = fmaxf(a, 0.0f);
    }
    __syncthreads();
    int b = t >> 7, c = t & 127;
    float a = gb2[c];
    for (int m = 0; m < MID; ++m) a += gw2[c * MID + m] * hid[b][m];
    gout[t] = a;
}

// ---------------------------------------------------------------------------
// Kernel 3: fused local-MLP gate + per-block blend.
// One block per (b, dc, hc): 32 coarse voxels (full W), all 128 channels.
//   out[2x2x2 block] = w * x + (1-w) * mean(block)
//   w = sigmoid(gout[b,c] + MLP_l(2sqrt2 * corner)[c, voxel])
// ---------------------------------------------------------------------------
__global__ __launch_bounds__(256) void main_kernel(const float* __restrict__ x,
                                                   const float* __restrict__ lw1,
                                                   const float* __restrict__ lb1,
                                                   const float* __restrict__ lw2,
                                                   const float* __restrict__ lb2,
                                                   const float* __restrict__ gout,
                                                   float* __restrict__ out) {
    __shared__ float xs[C_ * 32];    // x_sum[c][wc]; reused as w[c][wc] after MLP
    __shared__ float hid[MID * 32];  // hidden[m][wc]
    __shared__ float slw1[MID * C_];
    __shared__ float slw2[C_ * MID];
    __shared__ float slb1[MID];
    __shared__ float slb2[C_];
    __shared__ float sgout[C_];

    const int blk = blockIdx.x;      // b*1024 + dc*32 + hc
    const int b  = blk >> 10;
    const int dc = (blk >> 5) & 31;
    const int hc = blk & 31;
    const int tid = threadIdx.x;

    // stage weights into LDS
    for (int i = tid; i < MID * C_; i += 256) slw1[i] = lw1[i];
    for (int i = tid; i < C_ * MID; i += 256) slw2[i] = lw2[i];
    if (tid < MID) slb1[tid] = lb1[tid];
    if (tid < C_) { slb2[tid] = lb2[tid]; sgout[tid] = gout[b * C_ + tid]; }

    const float* xb = x + (size_t)b * C_ * CS;
    float* ob = out + (size_t)b * C_ * CS;
    const int rowoff = ((2 * dc) * 64 + 2 * hc) * 64;   // float offset of (p=0,q=0) row

    // ---- stage 1: corner samples -> x_sum in LDS ----
    {
        int c = tid >> 5, f2 = tid & 31;
        for (int it = 0; it < 16; ++it, c += 8) {
            const float2* row = (const float2*)(xb + (size_t)c * CS + rowoff);
            xs[c * 32 + f2] = SQRT8 * row[f2].x;
        }
    }
    __syncthreads();

    // ---- stage 2a: hidden[m][wc] = relu(lw1 @ xsum + lb1) ----
    {
        int m = tid >> 5, wc = tid & 31;
        float a = slb1[m];
        for (int c = 0; c < C_; ++c) a += slw1[m * C_ + c] * xs[c * 32 + wc];
        hid[m * 32 + wc] = fmaxf(a, 0.0f);
    }
    __syncthreads();

    // ---- stage 2b: w[c][wc] = sigmoid(lw2 @ hid + lb2 + gout)  (overwrites xs) ----
    {
        int wc = tid & 31, c0 = tid >> 5;
        float hv[MID];
        for (int m = 0; m < MID; ++m) hv[m] = hid[m * 32 + wc];
        for (int i = 0; i < 16; ++i) {
            int c = c0 * 16 + i;
            float a = slb2[c] + sgout[c];
            for (int m = 0; m < MID; ++m) a += slw2[c * MID + m] * hv[m];
            xs[c * 32 + wc] = sigmoidf_(a);
        }
    }
    __syncthreads();

    // ---- stage 3: blend each 2x2x2 block with its mean ----
    {
        int wc = tid & 31, cg = tid >> 5;       // 8 channel-groups
        for (int it = 0; it < 16; ++it) {
            int c = cg + 8 * it;
            const float* base = xb + (size_t)c * CS + rowoff;
            float* obase = ob + (size_t)c * CS + rowoff;
            float2 a00 = ((const float2*)(base))[wc];
            float2 a01 = ((const float2*)(base + 64))[wc];
            float2 a10 = ((const float2*)(base + 4096))[wc];
            float2 a11 = ((const float2*)(base + 4096 + 64))[wc];
            float mean = (a00.x + a00.y + a01.x + a01.y +
                          a10.x + a10.y + a11.x + a11.y) * 0.125f;
            float wv = xs[c * 32 + wc];
            float om = (1.0f - wv) * mean;
            float2 o;
            o.x = wv * a00.x + om; o.y = wv * a00.y + om; ((float2*)(obase))[wc] = o;
            o.x = wv * a01.x + om; o.y = wv * a01.y + om; ((float2*)(obase + 64))[wc] = o;
            o.x = wv * a10.x + om; o.y = wv * a10.y + om; ((float2*)(obase + 4096))[wc] = o;
            o.x = wv * a11.x + om; o.y = wv * a11.y + om; ((float2*)(obase + 4096 + 64))[wc] = o;
        }
    }
}

extern "C" void kernel_launch(void* const* d_in, const int* in_sizes, int n_in,
                              void* d_out, int out_size, void* d_ws, size_t ws_size,
                              hipStream_t stream) {
    const float* x   = (const float*)d_in[0];
    const float* gw1 = (const float*)d_in[1];
    const float* gb1 = (const float*)d_in[2];
    const float* gw2 = (const float*)d_in[3];
    const float* gb2 = (const float*)d_in[4];
    const float* lw1 = (const float*)d_in[5];
    const float* lb1 = (const float*)d_in[6];
    const float* lw2 = (const float*)d_in[7];
    const float* lb2 = (const float*)d_in[8];
    float* o  = (float*)d_out;
    float* ws = (float*)d_ws;      // [0..255] gap, [256..511] gout

    gap_kernel<<<256, 256, 0, stream>>>(x, ws);
    gmlp_kernel<<<1, 256, 0, stream>>>(ws, gw1, gb1, gw2, gb2, ws + 256);
    main_kernel<<<2048, 256, 0, stream>>>(x, lw1, lb1, lw2, lb2, ws + 256, o);
}

// Round 2
// 489.777 us; speedup vs baseline: 1.0715x; 1.0715x over previous
//
#include <hip/hip_runtime.h>
#include <math.h>

#define C_ 128
#define MID 8
#define CS 262144            // channel stride = 64*64*64 floats
#define SQRT8 2.8284271247461903f   // 2*sqrt(2)

static __device__ __forceinline__ float sigmoidf_(float z) {
    return 1.0f / (1.0f + __expf(-z));
}

// ---------------------------------------------------------------------------
// K1: one block per (b, dc, hc). Reads the 128 corner rows (float4, keep
// .x/.z), stages 2sqrt2*corner = x_sum into LDS, runs the local 128->8->128
// MLP, writes pre-sigmoid lout[b][dc][hc][c][wc] to global, and emits
// per-(block, c) partial sums of raw corners for the gap reduction.
// ---------------------------------------------------------------------------
__global__ __launch_bounds__(256) void corner_kernel(
    const float* __restrict__ x,
    const float* __restrict__ lw1, const float* __restrict__ lb1,
    const float* __restrict__ lw2, const float* __restrict__ lb2,
    float* __restrict__ partial,   // [2048][128]
    float* __restrict__ lout)      // [2][32][32][128][32]
{
    __shared__ float xs[C_ * 33];      // x_sum[c][wc], stride 33 (bank spread)
    __shared__ float hid[MID * 32];
    __shared__ float slw1[MID * C_];
    __shared__ float slw2[C_ * MID];

    const int blk = blockIdx.x;        // b*1024 + dc*32 + hc
    const int b  = blk >> 10;
    const int dc = (blk >> 5) & 31;
    const int hc = blk & 31;
    const int tid = threadIdx.x;

    for (int i = tid; i < MID * C_; i += 256) slw1[i] = lw1[i];
    for (int i = tid; i < C_ * MID; i += 256) slw2[i] = lw2[i];

    const float* xb = x + (size_t)b * C_ * CS + (size_t)(((2 * dc) * 64 + 2 * hc) * 64);
    const int f = tid & 15;
    {
        int c = tid >> 4;
        #pragma unroll
        for (int k = 0; k < 8; ++k, c += 16) {
            float4 v = ((const float4*)(xb + (size_t)c * CS))[f];
            xs[c * 33 + 2 * f]     = SQRT8 * v.x;
            xs[c * 33 + 2 * f + 1] = SQRT8 * v.z;
            float sc = v.x + v.z;                  // raw corner partial for gap
            sc += __shfl_down(sc, 8);
            sc += __shfl_down(sc, 4);
            sc += __shfl_down(sc, 2);
            sc += __shfl_down(sc, 1);
            if (f == 0) partial[blk * C_ + c] = sc;
        }
    }
    __syncthreads();

    // hidden[m][wc] = relu(lw1 @ x_sum + lb1)
    {
        int m = tid >> 5, wc = tid & 31;
        float a = lb1[m];
        for (int cc = 0; cc < C_; ++cc) a += slw1[m * C_ + cc] * xs[cc * 33 + wc];
        hid[m * 32 + wc] = fmaxf(a, 0.0f);
    }
    __syncthreads();

    // lout[c][wc] = lw2 @ hidden + lb2   (pre-sigmoid, no gout yet)
    {
        int wc = tid & 31, c0 = tid >> 5;
        float hv[MID];
        #pragma unroll
        for (int m = 0; m < MID; ++m) hv[m] = hid[m * 32 + wc];
        float* lo = lout + (size_t)blk * (C_ * 32);
        #pragma unroll
        for (int i = 0; i < 16; ++i) {
            int cc = c0 * 16 + i;
            float a = lb2[cc];
            #pragma unroll
            for (int m = 0; m < MID; ++m) a += slw2[cc * MID + m] * hv[m];
            lo[cc * 32 + wc] = a;
        }
    }
}

// ---------------------------------------------------------------------------
// K2: one block per batch b. Reduce 1024 per-block partials per channel ->
// gap, then the global 128->8->128 MLP -> gout[b*128+c].
// ---------------------------------------------------------------------------
__global__ __launch_bounds__(1024) void gmlp_kernel(
    const float* __restrict__ partial,
    const float* __restrict__ gw1, const float* __restrict__ gb1,
    const float* __restrict__ gw2, const float* __restrict__ gb2,
    float* __restrict__ gout)
{
    __shared__ float red[8][C_];
    __shared__ float sgap[C_];
    __shared__ float shid[MID];
    const int b = blockIdx.x;
    const int t = threadIdx.x;
    const int c = t & 127, chunk = t >> 7;
    float s = 0.0f;
    const float* p = partial + (size_t)(b * 1024 + chunk * 128) * C_ + c;
    for (int j = 0; j < 128; ++j) s += p[(size_t)j * C_];
    red[chunk][c] = s;
    __syncthreads();
    if (t < C_) {
        float tot = 0.0f;
        #pragma unroll
        for (int k = 0; k < 8; ++k) tot += red[k][c];
        sgap[c] = tot * (SQRT8 / 32768.0f);
    }
    __syncthreads();
    if (t < MID) {
        float a = gb1[t];
        for (int cc = 0; cc < C_; ++cc) a += gw1[t * C_ + cc] * sgap[cc];
        shid[t] = fmaxf(a, 0.0f);
    }
    __syncthreads();
    if (t < C_) {
        float a = gb2[t];
        #pragma unroll
        for (int m = 0; m < MID; ++m) a += gw2[t * MID + m] * shid[m];
        gout[b * C_ + t] = a;
    }
}

// ---------------------------------------------------------------------------
// K3: pure streaming blend. One block per (b, c, dc, half-of-hc); each thread
// owns one float4 column of a 2x2x2x4 slab: 4 float4 loads, gate float2,
// 4 float4 stores.  out = w*x + (1-w)*block_mean.
// ---------------------------------------------------------------------------
__global__ __launch_bounds__(256) void blend_kernel(
    const float* __restrict__ x,
    const float* __restrict__ lout,
    const float* __restrict__ gout,
    float* __restrict__ out)
{
    const int blk  = blockIdx.x;       // b*8192 + c*64 + dc*2 + half
    const int half = blk & 1;
    const int dc   = (blk >> 1) & 31;
    const int c    = (blk >> 6) & 127;
    const int b    = blk >> 13;
    const int tid  = threadIdx.x;
    const int f    = tid & 15;
    const int hc   = half * 16 + (tid >> 4);

    const size_t off = (size_t)(b * C_ + c) * CS
                     + (size_t)(2 * dc) * 4096 + (size_t)(2 * hc) * 64;
    float4 a00 = ((const float4*)(x + off))[f];
    float4 a01 = ((const float4*)(x + off + 64))[f];
    float4 a10 = ((const float4*)(x + off + 4096))[f];
    float4 a11 = ((const float4*)(x + off + 4160))[f];

    const float go = gout[b * C_ + c];
    const float2 g2 = *(const float2*)(lout
        + ((size_t)(((b * 32 + dc) * 32 + hc) * C_ + c)) * 32 + 2 * f);
    const float w0 = sigmoidf_(g2.x + go);
    const float w1 = sigmoidf_(g2.y + go);
    const float mean0 = (a00.x + a00.y + a01.x + a01.y +
                         a10.x + a10.y + a11.x + a11.y) * 0.125f;
    const float mean1 = (a00.z + a00.w + a01.z + a01.w +
                         a10.z + a10.w + a11.z + a11.w) * 0.125f;
    const float om0 = (1.0f - w0) * mean0;
    const float om1 = (1.0f - w1) * mean1;

    float4 o;
    o.x = w0 * a00.x + om0; o.y = w0 * a00.y + om0;
    o.z = w1 * a00.z + om1; o.w = w1 * a00.w + om1;
    ((float4*)(out + off))[f] = o;
    o.x = w0 * a01.x + om0; o.y = w0 * a01.y + om0;
    o.z = w1 * a01.z + om1; o.w = w1 * a01.w + om1;
    ((float4*)(out + off + 64))[f] = o;
    o.x = w0 * a10.x + om0; o.y = w0 * a10.y + om0;
    o.z = w1 * a10.z + om1; o.w = w1 * a10.w + om1;
    ((float4*)(out + off + 4096))[f] = o;
    o.x = w0 * a11.x + om0; o.y = w0 * a11.y + om0;
    o.z = w1 * a11.z + om1; o.w = w1 * a11.w + om1;
    ((float4*)(out + off + 4160))[f] = o;
}

extern "C" void kernel_launch(void* const* d_in, const int* in_sizes, int n_in,
                              void* d_out, int out_size, void* d_ws, size_t ws_size,
                              hipStream_t stream) {
    const float* x   = (const float*)d_in[0];
    const float* gw1 = (const float*)d_in[1];
    const float* gb1 = (const float*)d_in[2];
    const float* gw2 = (const float*)d_in[3];
    const float* gb2 = (const float*)d_in[4];
    const float* lw1 = (const float*)d_in[5];
    const float* lb1 = (const float*)d_in[6];
    const float* lw2 = (const float*)d_in[7];
    const float* lb2 = (const float*)d_in[8];
    float* o  = (float*)d_out;
    float* ws = (float*)d_ws;

    float* partial = ws;               // 2048*128   = 262144 floats (1 MiB)
    float* gout    = ws + 262144;      // 256 floats
    float* lout    = ws + 262400;      // 2*32*32*128*32 = 8388608 floats (32 MiB)

    corner_kernel<<<2048, 256, 0, stream>>>(x, lw1, lb1, lw2, lb2, partial, lout);
    gmlp_kernel<<<2, 1024, 0, stream>>>(partial, gw1, gb1, gw2, gb2, gout);
    blend_kernel<<<16384, 256, 0, stream>>>(x, lout, gout, o);
}